// Round 3
// baseline (1409.143 us; speedup 1.0000x reference)
//
#include <hip/hip_runtime.h>
#include <stdint.h>
#include <stddef.h>

typedef unsigned short u16;
typedef __bf16 bf16x8 __attribute__((ext_vector_type(8)));
typedef float f32x4 __attribute__((ext_vector_type(4)));
typedef u16 u16x8 __attribute__((ext_vector_type(8)));

#define B_    2
#define L_    256
#define D_    4096
#define H_    32
#define DH_   128
#define SINK_ 128
#define S_    4224
#define WINS_ 3968   /* S - L */
#define M_    512    /* B*L   */
#define SPLIT_ 4     /* in-block flash S-splits */

__device__ __forceinline__ float bf2f(u16 u){
  union { float f; uint32_t i; } v; v.i = ((uint32_t)u) << 16; return v.f;
}
__device__ __forceinline__ u16 f2bf(float f){
  union { float f; uint32_t i; } v; v.f = f;
  return (u16)((v.i + 0x7fffu + ((v.i >> 16) & 1u)) >> 16);
}
__device__ __forceinline__ bf16x8 ld8(const u16* p){
  return __builtin_bit_cast(bf16x8, *(const u16x8*)p);
}
// 8 consecutive f32 -> bf16x8 fragment
__device__ __forceinline__ bf16x8 ld8f(const float* p){
  f32x4 a = *(const f32x4*)p;
  f32x4 b = *(const f32x4*)(p + 4);
  u16x8 r;
  r[0] = f2bf(a[0]); r[1] = f2bf(a[1]); r[2] = f2bf(a[2]); r[3] = f2bf(a[3]);
  r[4] = f2bf(b[0]); r[5] = f2bf(b[1]); r[6] = f2bf(b[2]); r[7] = f2bf(b[3]);
  return __builtin_bit_cast(bf16x8, r);
}

// ---------------------------------------------------------------------------
// Dtype detector: if x is f32, the even u16 half-words are low mantissa bits
// (uniform 16-bit patterns -> some of 1024 samples are huge/NaN as bf16).
// If x is bf16, even half-words are true N(0,1) samples (|v| < 10).
// mode: 1 = f32 layout, 0 = bf16 layout.
// ---------------------------------------------------------------------------
__global__ void detect_k(const u16* __restrict__ x, uint32_t* __restrict__ flag){
  const int lane = threadIdx.x & 63;
  int bad = 0;
  for (int i = lane; i < 1024; i += 64){
    float v = bf2f(x[2 * i]);
    if (!(v * 0.0f == 0.0f) || fabsf(v) > 1e6f) bad = 1;  // NaN/inf or huge
  }
#pragma unroll
  for (int m = 1; m < 64; m <<= 1) bad |= __shfl_xor(bad, m, 64);
  if (threadIdx.x == 0) *flag = (uint32_t)(bad ? 1 : 0);
}

// ---------------------------------------------------------------------------
// Transpose + convert: WT[n][k] = (bf16)W[k][n], W is f32 or bf16 per mode.
// ---------------------------------------------------------------------------
__global__ __launch_bounds__(256) void transpose_k(const void* __restrict__ W,
                                                   u16* __restrict__ WT,
                                                   const uint32_t* __restrict__ flag){
  const int mode = (int)*flag;
  __shared__ u16 Ts[64 * 68];  // pad 68 to break bank collapse
  const int t  = threadIdx.x;
  const int k0 = blockIdx.x * 64;
  const int n0 = blockIdx.y * 64;
  const int r  = t >> 2;           // 0..63
  const int c  = (t & 3) * 8;      // 0,8,16,24
  const size_t rowoff = (size_t)(k0 + r) * 4096;
#pragma unroll
  for (int p = 0; p < 2; p++){
    const int cc = c + p * 32;
    u16x8 v;
    if (mode){
      const float* pf = (const float*)W + rowoff + n0 + cc;
      f32x4 a = *(const f32x4*)pf;
      f32x4 b = *(const f32x4*)(pf + 4);
      v[0] = f2bf(a[0]); v[1] = f2bf(a[1]); v[2] = f2bf(a[2]); v[3] = f2bf(a[3]);
      v[4] = f2bf(b[0]); v[5] = f2bf(b[1]); v[6] = f2bf(b[2]); v[7] = f2bf(b[3]);
    } else {
      v = *(const u16x8*)((const u16*)W + rowoff + n0 + cc);
    }
#pragma unroll
    for (int j = 0; j < 8; j++) Ts[r * 68 + cc + j] = v[j];
  }
  __syncthreads();
#pragma unroll
  for (int p = 0; p < 2; p++){
    const int kc = c + p * 32;
    u16x8 v;
#pragma unroll
    for (int j = 0; j < 8; j++) v[j] = Ts[(kc + j) * 68 + r];
    *(u16x8*)(WT + (size_t)(n0 + r) * 4096 + k0 + kc) = v;
  }
}

// ---------------------------------------------------------------------------
// GEMM, BN=64: C[M,4096] = A[M,4096] * W_wi, BT3 = concatenated W^T bf16.
// grid.x = 64 * n_weights (wi = blockIdx.x>>6), grid.y = 8 (m-tiles of 64).
// BM=64 BN=64 BK=32, 256 thr = 4 waves, wave tile 32x32 (2x2 MFMA tiles).
// Fused-QKV: one launch, 1536 blocks = 6 blocks/CU (vs 1/CU before).
// a_ext: A external (f32 when mode). c_ext: C external (f32 when mode).
// C (bf16 path) goes to Cout + wi*M_*4096.
// ---------------------------------------------------------------------------
__global__ __launch_bounds__(256) void gemm64_k(const void* __restrict__ Ain,
                                                const u16* __restrict__ BT3,
                                                void* __restrict__ Cout,
                                                const uint32_t* __restrict__ flag,
                                                int a_ext, int c_ext){
  const int mode = (int)*flag;
  const int a_f32 = a_ext & mode;
  const int c_f32 = c_ext & mode;

  const int bx = blockIdx.x;
  const int wi = bx >> 6;               // weight index (0 when grid.x == 64)
  const int n0 = (bx & 63) * 64;
  const int m0 = blockIdx.y * 64;
  const u16* BT = BT3 + (size_t)wi * (4096ull * 4096);

  __shared__ u16 As[64 * 32];    // 4KB
  __shared__ u16 Bs[64 * 32];    // 4KB

  const int t    = threadIdx.x;
  const int w    = t >> 6;
  const int lane = t & 63;
  const int wm   = w >> 1;          // 0..1
  const int wn   = w & 1;           // 0..1
  const int mq   = lane & 15;
  const int qd   = lane >> 4;

  f32x4 acc[2][2] = {};

  const size_t ga = (size_t)(m0 + (t >> 2)) * 4096 + (t & 3) * 8;
  const size_t gb = (size_t)(n0 + (t >> 2)) * 4096 + (t & 3) * 8;

  for (int kt = 0; kt < 128; kt++){
    const int k0 = kt * 32;
    u16x8 av;
    if (a_f32){
      const float* pa = (const float*)Ain + ga + k0;
      f32x4 a = *(const f32x4*)pa;
      f32x4 b = *(const f32x4*)(pa + 4);
      av[0] = f2bf(a[0]); av[1] = f2bf(a[1]); av[2] = f2bf(a[2]); av[3] = f2bf(a[3]);
      av[4] = f2bf(b[0]); av[5] = f2bf(b[1]); av[6] = f2bf(b[2]); av[7] = f2bf(b[3]);
    } else {
      av = *(const u16x8*)((const u16*)Ain + ga + k0);
    }
    u16x8 bv = *(const u16x8*)(BT + gb + k0);
    __syncthreads();                 // previous iter's frag reads complete
    *(u16x8*)&As[t * 8] = av;
    *(u16x8*)&Bs[t * 8] = bv;
    __syncthreads();                 // staging visible to all waves

    bf16x8 af[2], bfr[2];
#pragma unroll
    for (int i = 0; i < 2; i++)
      af[i] = ld8(&As[(wm * 32 + i * 16 + mq) * 32 + qd * 8]);
#pragma unroll
    for (int j = 0; j < 2; j++)
      bfr[j] = ld8(&Bs[(wn * 32 + j * 16 + mq) * 32 + qd * 8]);
#pragma unroll
    for (int i = 0; i < 2; i++)
#pragma unroll
      for (int j = 0; j < 2; j++)
        acc[i][j] = __builtin_amdgcn_mfma_f32_16x16x32_bf16(af[i], bfr[j], acc[i][j], 0, 0, 0);
  }

  // epilogue: C/D layout col=lane&15, row=(lane>>4)*4+reg
  u16* cu = (u16*)Cout + (size_t)wi * ((size_t)M_ * 4096);
#pragma unroll
  for (int i = 0; i < 2; i++)
#pragma unroll
    for (int j = 0; j < 2; j++)
#pragma unroll
      for (int r = 0; r < 4; r++){
        const int row = m0 + wm * 32 + i * 16 + qd * 4 + r;
        const int col = n0 + wn * 32 + j * 16 + mq;
        if (c_f32) ((float*)Cout)[(size_t)row * 4096 + col] = acc[i][j][r];
        else       cu[(size_t)row * 4096 + col]             = f2bf(acc[i][j][r]);
      }
}

// ---------------------------------------------------------------------------
// Per-head RMSNorm on internal bf16 rows of 128; norm weights external.
// grid.x = 4096 (4 rows/block), grid.y: 0=q (wq), 1=k (wk)
// ---------------------------------------------------------------------------
__global__ __launch_bounds__(256) void rmsnorm_k(const u16* __restrict__ src,
                                                 u16* __restrict__ dst,
                                                 const void* __restrict__ wq,
                                                 const void* __restrict__ wk,
                                                 const uint32_t* __restrict__ flag){
  const int mode = (int)*flag;
  const int t = threadIdx.x, w = t >> 6, lane = t & 63;
  const size_t base = (size_t)blockIdx.y * (size_t)M_ * 4096;
  const int rid = blockIdx.x * 4 + w;  // 0..16383
  const u16* s = src + base + (size_t)rid * 128 + lane * 2;
  u16*       d = dst + base + (size_t)rid * 128 + lane * 2;
  const void* wp = blockIdx.y ? wk : wq;
  float w0, w1;
  if (mode){ w0 = ((const float*)wp)[lane * 2]; w1 = ((const float*)wp)[lane * 2 + 1]; }
  else     { w0 = bf2f(((const u16*)wp)[lane * 2]); w1 = bf2f(((const u16*)wp)[lane * 2 + 1]); }
  const float f0 = bf2f(s[0]), f1 = bf2f(s[1]);
  float ss = f0 * f0 + f1 * f1;
#pragma unroll
  for (int m = 1; m < 64; m <<= 1) ss += __shfl_xor(ss, m, 64);
  const float rinv = rsqrtf(ss * (1.0f / 128.0f) + 1e-6f);
  d[0] = f2bf(f0 * rinv * w0);
  d[1] = f2bf(f1 * rinv * w1);
}

// ---------------------------------------------------------------------------
// Flash attention, in-block S-split, 2 blocks/CU.
// grid = 512 blocks (b, h, qtile of 32), 512 threads = 8 waves =
// 4 S-split groups x 2 q-waves (16 q-rows each). Two independent blocks per
// CU decouple barrier drains. V for chunk sc+1 is prefetched into the
// (freed) staging registers right after VT is staged, so its latency hides
// under the QK^T/softmax/PV compute.
// ---------------------------------------------------------------------------
__global__ __launch_bounds__(512, 4) void attn_k(const u16* __restrict__ qn,
                                                 const u16* __restrict__ kn,
                                                 const u16* __restrict__ vnew,
                                                 const void* __restrict__ ck,
                                                 const void* __restrict__ cv,
                                                 u16* __restrict__ ao,
                                                 const uint32_t* __restrict__ flag){
  const int mode = (int)*flag;
  // 51200 B LDS, reused: main = VT[4][128*40] u16 (40960) + PB[8][16*40] u16
  // (10240); merge = OB[32][128] f32 (16384) + ML[4][32][2] f32 (1024).
  __shared__ __align__(16) unsigned char LDSB[51200];
  u16*   VTall = (u16*)LDSB;
  u16*   PBall = (u16*)(LDSB + 40960);
  float* OB    = (float*)LDSB;
  float* ML    = (float*)(LDSB + 16384);

  const int t  = threadIdx.x;    // 0..511
  const int W  = t >> 6;         // wave 0..7
  const int sp = W >> 1;         // S-split group 0..3
  const int w  = W & 1;          // q-wave within group 0..1
  const int lane = t & 63;
  const int lt = t & 127;        // thread within split group (128 threads)
  const int blk = blockIdx.x;    // 0..511
  const int b  = blk >> 8;
  const int h  = (blk >> 3) & 31;
  const int qt = blk & 7;        // 32-row q tile
  const int q0 = qt * 32 + w * 16;
  const int mq = lane & 15;
  const int qd = lane >> 4;

  u16* VT = VTall + sp * (128 * 40);   // this group's V^T chunk [d][s], pad 40
  u16* pb = PBall + W * 640;           // this wave's P tile [16][40]

  // Q fragments (A-operand: m=lane&15, k=quad*8+j), 4 k-chunks of 32
  bf16x8 aq[4];
  {
    const u16* qp = qn + ((size_t)(b * L_ + q0 + mq)) * 4096 + h * 128 + qd * 8;
#pragma unroll
    for (int kc = 0; kc < 4; kc++) aq[kc] = ld8(qp + kc * 32);
  }

  f32x4 oacc[8] = {};
  float mi[4], li[4];
#pragma unroll
  for (int r = 0; r < 4; r++){ mi[r] = -1e30f; li[r] = 0.f; }

  const int nchunks = (WINS_ + qt * 32 + 63) / 32;       // 125 + qt
  const int cpb = (nchunks + SPLIT_ - 1) / SPLIT_;       // block-uniform
  const int sc_beg = sp * cpb;
  const int sc_end = (sc_beg + cpb < nchunks) ? (sc_beg + cpb) : nchunks;
  const float scale = 0.08838834764831845f;
  const float L2E = 1.4426950408889634f;

  const int dd = lt;             // this thread's d column (0..127)
  u16x8 vv[4];                   // 32 s-values for column dd (4 x 8)

  auto loadV = [&](int sc){
    const int s0c = sc * 32;
#pragma unroll
    for (int c = 0; c < 4; c++){
#pragma unroll
      for (int j = 0; j < 8; j++){
        const int s = s0c + c * 8 + j;
        u16 val;
        if (s >= WINS_){
          val = vnew[((size_t)(b * L_ + (s - WINS_)) << 12) + h * 128 + dd];
        } else {
          const int scc = (s < SINK_) ? s : (s + L_);
          const size_t off = ((((size_t)b * S_ + scc) * H_ + h) << 7) + dd;
          val = mode ? f2bf(((const float*)cv)[off]) : ((const u16*)cv)[off];
        }
        vv[c][j] = val;
      }
    }
  };

  if (sc_beg < sc_end) loadV(sc_beg);

  for (int scr = 0; scr < cpb; scr++){     // uniform trip count for barriers
    const int sc = sc_beg + scr;
    const int act = (sc < sc_end);
    const int s0 = sc * 32;

    __syncthreads();   // previous iteration's VT reads complete (all groups)
    if (act){
#pragma unroll
      for (int c = 0; c < 4; c++)
        *(u16x8*)&VT[dd * 40 + c * 8] = vv[c];
    }
    __syncthreads();   // VT staged (all groups)
    if (sc + 1 < sc_end) loadV(sc + 1);    // prefetch next chunk's V (vv free)

    if (act){
      // ---- QK^T: logits[q][s], 2 s-tiles of 16 ----
      float lg[2][4];
#pragma unroll
      for (int st = 0; st < 2; st++){
        const int s = s0 + st * 16 + mq;
        f32x4 a = {};
        if (s0 + st * 16 >= WINS_){       // uniform: tiles are 16-aligned
          const u16* kp = kn + ((size_t)(b * L_ + (s - WINS_)) << 12) + h * 128;
#pragma unroll
          for (int kc = 0; kc < 4; kc++)
            a = __builtin_amdgcn_mfma_f32_16x16x32_bf16(aq[kc], ld8(kp + kc * 32 + qd * 8), a, 0, 0, 0);
        } else if (mode){
          const int scc = (s < SINK_) ? s : (s + L_);
          const float* kp = (const float*)ck + ((((size_t)b * S_ + scc) * H_ + h) << 7);
#pragma unroll
          for (int kc = 0; kc < 4; kc++)
            a = __builtin_amdgcn_mfma_f32_16x16x32_bf16(aq[kc], ld8f(kp + kc * 32 + qd * 8), a, 0, 0, 0);
        } else {
          const int scc = (s < SINK_) ? s : (s + L_);
          const u16* kp = (const u16*)ck + ((((size_t)b * S_ + scc) * H_ + h) << 7);
#pragma unroll
          for (int kc = 0; kc < 4; kc++)
            a = __builtin_amdgcn_mfma_f32_16x16x32_bf16(aq[kc], ld8(kp + kc * 32 + qd * 8), a, 0, 0, 0);
        }
#pragma unroll
        for (int r = 0; r < 4; r++) lg[st][r] = a[r] * scale;
      }
      // ---- causal mask (only near/past the frontier) ----
      if (s0 + 31 > WINS_ + q0){
#pragma unroll
        for (int st = 0; st < 2; st++){
          const int s = s0 + st * 16 + mq;
#pragma unroll
          for (int r = 0; r < 4; r++)
            if (s > WINS_ + (q0 + qd * 4 + r)) lg[st][r] = -1e30f;
        }
      }
      // ---- online softmax (row r spread over 16 mq lanes within quad) ----
      float p[2][4];
#pragma unroll
      for (int r = 0; r < 4; r++){
        float mx = fmaxf(lg[0][r], lg[1][r]);
#pragma unroll
        for (int m = 1; m < 16; m <<= 1) mx = fmaxf(mx, __shfl_xor(mx, m, 64));
        const float mnew = fmaxf(mi[r], mx);
        const float alpha = exp2f((mi[r] - mnew) * L2E);
        mi[r] = mnew;
        float s_ = 0.f;
#pragma unroll
        for (int st = 0; st < 2; st++){
          p[st][r] = exp2f((lg[st][r] - mnew) * L2E);
          s_ += p[st][r];
        }
#pragma unroll
        for (int m = 1; m < 16; m <<= 1) s_ += __shfl_xor(s_, m, 64);
        li[r] = li[r] * alpha + s_;
#pragma unroll
        for (int nt = 0; nt < 8; nt++) oacc[nt][r] *= alpha;
      }
      // ---- P: C-layout -> A-layout via wave-private LDS ----
#pragma unroll
      for (int st = 0; st < 2; st++)
#pragma unroll
        for (int r = 0; r < 4; r++)
          pb[(qd * 4 + r) * 40 + st * 16 + mq] = f2bf(p[st][r]);
      asm volatile("" ::: "memory");
      u16x8 pr;
#pragma unroll
      for (int j = 0; j < 8; j++) pr[j] = pb[mq * 40 + qd * 8 + j];
      bf16x8 ap = __builtin_bit_cast(bf16x8, pr);
      // ---- PV: O[q][d] += P * V ----
#pragma unroll
      for (int nt = 0; nt < 8; nt++){
        bf16x8 bv = ld8(&VT[(nt * 16 + mq) * 40 + qd * 8]);
        oacc[nt] = __builtin_amdgcn_mfma_f32_16x16x32_bf16(ap, bv, oacc[nt], 0, 0, 0);
      }
    }
  }

  // ---- intra-block merge of the 4 S-split partials ----
  __syncthreads();                       // (A) main phase done, VT/PB free
  if (mq == 0){
#pragma unroll
    for (int r = 0; r < 4; r++){
      const int lr = w * 16 + qd * 4 + r;     // local row 0..31
      ML[(sp * 32 + lr) * 2 + 0] = mi[r];
      ML[(sp * 32 + lr) * 2 + 1] = li[r];
    }
  }
  __syncthreads();                       // (B) ML visible

  float gl[4], wgt[4];
#pragma unroll
  for (int r = 0; r < 4; r++){
    const int lr = w * 16 + qd * 4 + r;
    float m_ = -1e30f;
#pragma unroll
    for (int p = 0; p < SPLIT_; p++) m_ = fmaxf(m_, ML[(p * 32 + lr) * 2 + 0]);
    float l_ = 0.f;
#pragma unroll
    for (int p = 0; p < SPLIT_; p++)
      l_ += exp2f((ML[(p * 32 + lr) * 2 + 0] - m_) * L2E) * ML[(p * 32 + lr) * 2 + 1];
    gl[r] = l_;
    wgt[r] = exp2f((mi[r] - m_) * L2E);
  }

  // accumulation rounds: single-owner RMW per element, barrier-separated
#pragma unroll
  for (int p = 0; p < SPLIT_; p++){
    if (sp == p){
#pragma unroll
      for (int nt = 0; nt < 8; nt++)
#pragma unroll
        for (int r = 0; r < 4; r++){
          const int off = (w * 16 + qd * 4 + r) * 128 + nt * 16 + mq;
          const float v = wgt[r] * oacc[nt][r];
          if (p == 0) OB[off] = v;
          else        OB[off] += v;
        }
    }
    __syncthreads();
  }

  // final write by group 0 (waves 0,1 cover the 32 rows)
  if (sp == 0){
#pragma unroll
    for (int nt = 0; nt < 8; nt++)
#pragma unroll
      for (int r = 0; r < 4; r++){
        const int lr = w * 16 + qd * 4 + r;
        const int qrow = qt * 32 + lr;
        const float v = OB[lr * 128 + nt * 16 + mq] / gl[r];
        ao[((size_t)(b * L_ + qrow) << 12) + h * 128 + nt * 16 + mq] = f2bf(v);
      }
  }
}

// ---------------------------------------------------------------------------
extern "C" void kernel_launch(void* const* d_in, const int* in_sizes, int n_in,
                              void* d_out, int out_size, void* d_ws, size_t ws_size,
                              hipStream_t stream){
  (void)in_sizes; (void)n_in; (void)out_size;
  const void* x  = d_in[0];
  const void* ck = d_in[1];
  const void* cv = d_in[2];
  const void* Wq = d_in[3];
  const void* Wk = d_in[4];
  const void* Wv = d_in[5];
  const void* Wo = d_in[6];
  const void* qw = d_in[7];
  const void* kw = d_in[8];

  const size_t WT_E = 4096ull * 4096;    // one transposed weight (bf16 elems)
  const size_t BUF  = (size_t)M_ * 4096; // 2.10M elems

  uint32_t* flag = (uint32_t*)d_ws;
  u16* ws0 = (u16*)d_ws + 64;            // skip 128B for flag

  detect_k<<<1, 64, 0, stream>>>((const u16*)x, flag);

  // Fused path needs 3 transposed weights resident: 128 + (3*WT_E + 6*BUF)*2 B
  const size_t need_fused = 128 + (3 * WT_E + 6 * BUF) * 2;
  if (ws_size >= need_fused){
    u16* WT3 = ws0;                      // 3 x WT_E (Wq^T, Wk^T, Wv^T; Wo^T reuses)
    u16* qkv = WT3 + 3 * WT_E;           // 3 x BUF (q_raw, k_raw, v)
    u16* qn  = qkv + 3 * BUF;            // 2 x BUF (qn, kn)
    u16* ao  = qn + 2 * BUF;             // 1 x BUF

    transpose_k<<<dim3(64, 64), 256, 0, stream>>>(Wq, WT3, flag);
    transpose_k<<<dim3(64, 64), 256, 0, stream>>>(Wk, WT3 + WT_E, flag);
    transpose_k<<<dim3(64, 64), 256, 0, stream>>>(Wv, WT3 + 2 * WT_E, flag);
    gemm64_k<<<dim3(192, 8), 256, 0, stream>>>(x, WT3, qkv, flag, 1, 0);

    rmsnorm_k<<<dim3(4096, 2), 256, 0, stream>>>(qkv, qn, qw, kw, flag);

    attn_k<<<dim3(512), 512, 0, stream>>>(qn, qn + BUF, qkv + 2 * BUF,
                                          ck, cv, ao, flag);

    transpose_k<<<dim3(64, 64), 256, 0, stream>>>(Wo, WT3, flag);
    gemm64_k<<<dim3(64, 8), 256, 0, stream>>>(ao, WT3, d_out, flag, 0, 1);
  } else {
    // Fallback: sequential per-weight path (round-2 layout)
    u16* WT  = ws0;                      // WT_E elems (reused per weight)
    u16* qkv = WT + WT_E;                // 3 x BUF
    u16* qn  = qkv + 3 * BUF;            // 2 x BUF
    u16* ao  = qn + 2 * BUF;             // 1 x BUF

    transpose_k<<<dim3(64, 64), 256, 0, stream>>>(Wq, WT, flag);
    gemm64_k<<<dim3(64, 8), 256, 0, stream>>>(x, WT, qkv, flag, 1, 0);
    transpose_k<<<dim3(64, 64), 256, 0, stream>>>(Wk, WT, flag);
    gemm64_k<<<dim3(64, 8), 256, 0, stream>>>(x, WT, qkv + BUF, flag, 1, 0);
    transpose_k<<<dim3(64, 64), 256, 0, stream>>>(Wv, WT, flag);
    gemm64_k<<<dim3(64, 8), 256, 0, stream>>>(x, WT, qkv + 2 * BUF, flag, 1, 0);

    rmsnorm_k<<<dim3(4096, 2), 256, 0, stream>>>(qkv, qn, qw, kw, flag);

    attn_k<<<dim3(512), 512, 0, stream>>>(qn, qn + BUF, qkv + 2 * BUF,
                                          ck, cv, ao, flag);

    transpose_k<<<dim3(64, 64), 256, 0, stream>>>(Wo, WT, flag);
    gemm64_k<<<dim3(64, 8), 256, 0, stream>>>(ao, WT, d_out, flag, 0, 1);
  }
}

// Round 4
// 1312.440 us; speedup vs baseline: 1.0737x; 1.0737x over previous
//
#include <hip/hip_runtime.h>
#include <stdint.h>
#include <stddef.h>

typedef unsigned short u16;
typedef __bf16 bf16x8 __attribute__((ext_vector_type(8)));
typedef float f32x4 __attribute__((ext_vector_type(4)));
typedef u16 u16x8 __attribute__((ext_vector_type(8)));

#define B_    2
#define L_    256
#define D_    4096
#define H_    32
#define DH_   128
#define SINK_ 128
#define S_    4224
#define WINS_ 3968   /* S - L */
#define M_    512    /* B*L   */
#define SPLIT_ 4     /* in-block flash S-splits */

__device__ __forceinline__ float bf2f(u16 u){
  union { float f; uint32_t i; } v; v.i = ((uint32_t)u) << 16; return v.f;
}
__device__ __forceinline__ u16 f2bf(float f){
  union { float f; uint32_t i; } v; v.f = f;
  return (u16)((v.i + 0x7fffu + ((v.i >> 16) & 1u)) >> 16);
}
__device__ __forceinline__ bf16x8 ld8(const u16* p){
  return __builtin_bit_cast(bf16x8, *(const u16x8*)p);
}
// 8 consecutive f32 -> bf16x8 fragment
__device__ __forceinline__ bf16x8 ld8f(const float* p){
  f32x4 a = *(const f32x4*)p;
  f32x4 b = *(const f32x4*)(p + 4);
  u16x8 r;
  r[0] = f2bf(a[0]); r[1] = f2bf(a[1]); r[2] = f2bf(a[2]); r[3] = f2bf(a[3]);
  r[4] = f2bf(b[0]); r[5] = f2bf(b[1]); r[6] = f2bf(b[2]); r[7] = f2bf(b[3]);
  return __builtin_bit_cast(bf16x8, r);
}

// ---------------------------------------------------------------------------
// Dtype detector: if x is f32, the even u16 half-words are low mantissa bits
// (uniform 16-bit patterns -> some of 1024 samples are huge/NaN as bf16).
// If x is bf16, even half-words are true N(0,1) samples (|v| < 10).
// mode: 1 = f32 layout, 0 = bf16 layout.
// ---------------------------------------------------------------------------
__global__ void detect_k(const u16* __restrict__ x, uint32_t* __restrict__ flag){
  const int lane = threadIdx.x & 63;
  int bad = 0;
  for (int i = lane; i < 1024; i += 64){
    float v = bf2f(x[2 * i]);
    if (!(v * 0.0f == 0.0f) || fabsf(v) > 1e6f) bad = 1;  // NaN/inf or huge
  }
#pragma unroll
  for (int m = 1; m < 64; m <<= 1) bad |= __shfl_xor(bad, m, 64);
  if (threadIdx.x == 0) *flag = (uint32_t)(bad ? 1 : 0);
}

// ---------------------------------------------------------------------------
// Transpose + convert: WT[n][k] = (bf16)W[k][n], W is f32 or bf16 per mode.
// ---------------------------------------------------------------------------
__global__ __launch_bounds__(256) void transpose_k(const void* __restrict__ W,
                                                   u16* __restrict__ WT,
                                                   const uint32_t* __restrict__ flag){
  const int mode = (int)*flag;
  __shared__ u16 Ts[64 * 68];  // pad 68 to break bank collapse
  const int t  = threadIdx.x;
  const int k0 = blockIdx.x * 64;
  const int n0 = blockIdx.y * 64;
  const int r  = t >> 2;           // 0..63
  const int c  = (t & 3) * 8;      // 0,8,16,24
  const size_t rowoff = (size_t)(k0 + r) * 4096;
#pragma unroll
  for (int p = 0; p < 2; p++){
    const int cc = c + p * 32;
    u16x8 v;
    if (mode){
      const float* pf = (const float*)W + rowoff + n0 + cc;
      f32x4 a = *(const f32x4*)pf;
      f32x4 b = *(const f32x4*)(pf + 4);
      v[0] = f2bf(a[0]); v[1] = f2bf(a[1]); v[2] = f2bf(a[2]); v[3] = f2bf(a[3]);
      v[4] = f2bf(b[0]); v[5] = f2bf(b[1]); v[6] = f2bf(b[2]); v[7] = f2bf(b[3]);
    } else {
      v = *(const u16x8*)((const u16*)W + rowoff + n0 + cc);
    }
#pragma unroll
    for (int j = 0; j < 8; j++) Ts[r * 68 + cc + j] = v[j];
  }
  __syncthreads();
#pragma unroll
  for (int p = 0; p < 2; p++){
    const int kc = c + p * 32;
    u16x8 v;
#pragma unroll
    for (int j = 0; j < 8; j++) v[j] = Ts[(kc + j) * 68 + r];
    *(u16x8*)(WT + (size_t)(n0 + r) * 4096 + k0 + kc) = v;
  }
}

// ---------------------------------------------------------------------------
// GEMM, BN=64: C[M,4096] = A[M,4096] * W_wi, BT3 = concatenated W^T bf16.
// grid.x = 64 * n_weights (wi = blockIdx.x>>6), grid.y = 8 (m-tiles of 64).
// BM=64 BN=64 BK=32, 256 thr = 4 waves, wave tile 32x32 (2x2 MFMA tiles).
// Fused-QKV: one launch, 1536 blocks = 6 blocks/CU.
// ---------------------------------------------------------------------------
__global__ __launch_bounds__(256) void gemm64_k(const void* __restrict__ Ain,
                                                const u16* __restrict__ BT3,
                                                void* __restrict__ Cout,
                                                const uint32_t* __restrict__ flag,
                                                int a_ext, int c_ext){
  const int mode = (int)*flag;
  const int a_f32 = a_ext & mode;
  const int c_f32 = c_ext & mode;

  const int bx = blockIdx.x;
  const int wi = bx >> 6;               // weight index (0 when grid.x == 64)
  const int n0 = (bx & 63) * 64;
  const int m0 = blockIdx.y * 64;
  const u16* BT = BT3 + (size_t)wi * (4096ull * 4096);

  __shared__ u16 As[64 * 32];    // 4KB
  __shared__ u16 Bs[64 * 32];    // 4KB

  const int t    = threadIdx.x;
  const int w    = t >> 6;
  const int lane = t & 63;
  const int wm   = w >> 1;          // 0..1
  const int wn   = w & 1;           // 0..1
  const int mq   = lane & 15;
  const int qd   = lane >> 4;

  f32x4 acc[2][2] = {};

  const size_t ga = (size_t)(m0 + (t >> 2)) * 4096 + (t & 3) * 8;
  const size_t gb = (size_t)(n0 + (t >> 2)) * 4096 + (t & 3) * 8;

  for (int kt = 0; kt < 128; kt++){
    const int k0 = kt * 32;
    u16x8 av;
    if (a_f32){
      const float* pa = (const float*)Ain + ga + k0;
      f32x4 a = *(const f32x4*)pa;
      f32x4 b = *(const f32x4*)(pa + 4);
      av[0] = f2bf(a[0]); av[1] = f2bf(a[1]); av[2] = f2bf(a[2]); av[3] = f2bf(a[3]);
      av[4] = f2bf(b[0]); av[5] = f2bf(b[1]); av[6] = f2bf(b[2]); av[7] = f2bf(b[3]);
    } else {
      av = *(const u16x8*)((const u16*)Ain + ga + k0);
    }
    u16x8 bv = *(const u16x8*)(BT + gb + k0);
    __syncthreads();                 // previous iter's frag reads complete
    *(u16x8*)&As[t * 8] = av;
    *(u16x8*)&Bs[t * 8] = bv;
    __syncthreads();                 // staging visible to all waves

    bf16x8 af[2], bfr[2];
#pragma unroll
    for (int i = 0; i < 2; i++)
      af[i] = ld8(&As[(wm * 32 + i * 16 + mq) * 32 + qd * 8]);
#pragma unroll
    for (int j = 0; j < 2; j++)
      bfr[j] = ld8(&Bs[(wn * 32 + j * 16 + mq) * 32 + qd * 8]);
#pragma unroll
    for (int i = 0; i < 2; i++)
#pragma unroll
      for (int j = 0; j < 2; j++)
        acc[i][j] = __builtin_amdgcn_mfma_f32_16x16x32_bf16(af[i], bfr[j], acc[i][j], 0, 0, 0);
  }

  // epilogue: C/D layout col=lane&15, row=(lane>>4)*4+reg
  u16* cu = (u16*)Cout + (size_t)wi * ((size_t)M_ * 4096);
#pragma unroll
  for (int i = 0; i < 2; i++)
#pragma unroll
    for (int j = 0; j < 2; j++)
#pragma unroll
      for (int r = 0; r < 4; r++){
        const int row = m0 + wm * 32 + i * 16 + qd * 4 + r;
        const int col = n0 + wn * 32 + j * 16 + mq;
        if (c_f32) ((float*)Cout)[(size_t)row * 4096 + col] = acc[i][j][r];
        else       cu[(size_t)row * 4096 + col]             = f2bf(acc[i][j][r]);
      }
}

// ---------------------------------------------------------------------------
// Per-head RMSNorm on internal bf16 rows of 128; norm weights external.
// grid.x = 4096 (4 rows/block), grid.y: 0=q (wq), 1=k (wk)
// ---------------------------------------------------------------------------
__global__ __launch_bounds__(256) void rmsnorm_k(const u16* __restrict__ src,
                                                 u16* __restrict__ dst,
                                                 const void* __restrict__ wq,
                                                 const void* __restrict__ wk,
                                                 const uint32_t* __restrict__ flag){
  const int mode = (int)*flag;
  const int t = threadIdx.x, w = t >> 6, lane = t & 63;
  const size_t base = (size_t)blockIdx.y * (size_t)M_ * 4096;
  const int rid = blockIdx.x * 4 + w;  // 0..16383
  const u16* s = src + base + (size_t)rid * 128 + lane * 2;
  u16*       d = dst + base + (size_t)rid * 128 + lane * 2;
  const void* wp = blockIdx.y ? wk : wq;
  float w0, w1;
  if (mode){ w0 = ((const float*)wp)[lane * 2]; w1 = ((const float*)wp)[lane * 2 + 1]; }
  else     { w0 = bf2f(((const u16*)wp)[lane * 2]); w1 = bf2f(((const u16*)wp)[lane * 2 + 1]); }
  const float f0 = bf2f(s[0]), f1 = bf2f(s[1]);
  float ss = f0 * f0 + f1 * f1;
#pragma unroll
  for (int m = 1; m < 64; m <<= 1) ss += __shfl_xor(ss, m, 64);
  const float rinv = rsqrtf(ss * (1.0f / 128.0f) + 1e-6f);
  d[0] = f2bf(f0 * rinv * w0);
  d[1] = f2bf(f1 * rinv * w1);
}

// ---------------------------------------------------------------------------
// Flash attention, in-block S-split (round-2 geometry: grid 256, qtile 64,
// 1024 thr = 16 waves = 4 S-split groups x 4 q-waves).
// New vs round 2: __launch_bounds__(1024,4) -> 128 VGPR cap, and K fragments
// are REGISTER-PREFETCHED one chunk ahead (kf[2][4]), issued right after
// QK^T consumes the previous set, so K HBM latency hides under
// softmax+PV+barrier+VT-stage. V prefetch as before.
// ---------------------------------------------------------------------------
__global__ __launch_bounds__(1024, 4) void attn_k(const u16* __restrict__ qn,
                                                  const u16* __restrict__ kn,
                                                  const u16* __restrict__ vnew,
                                                  const void* __restrict__ ck,
                                                  const void* __restrict__ cv,
                                                  u16* __restrict__ ao,
                                                  const uint32_t* __restrict__ flag){
  const int mode = (int)*flag;
  // 60 KB LDS, reused: main phase = VT[4][128*40] + PB[16][16*40] u16;
  // merge phase = OB[64][128] f32 (0..32768) + ML[4][64][2] f32 (32768..34816)
  __shared__ __align__(16) unsigned char LDSB[61440];
  u16*   VTall = (u16*)LDSB;
  u16*   PBall = (u16*)LDSB + 4 * 5120;
  float* OB    = (float*)LDSB;
  float* ML    = (float*)(LDSB + 32768);

  const int t  = threadIdx.x;
  const int W  = t >> 6;         // wave 0..15
  const int sp = W >> 2;         // S-split group 0..3
  const int w  = W & 3;          // q-wave within group 0..3
  const int lane = t & 63;
  const int lt = t & 255;        // thread within split group (256 threads)
  const int blk = blockIdx.x;
  const int b  = blk >> 7;
  const int h  = (blk >> 2) & 31;
  const int qt = blk & 3;
  const int q0 = qt * 64 + w * 16;
  const int mq = lane & 15;
  const int qd = lane >> 4;

  u16* VT = VTall + sp * (128 * 40);   // this group's V^T chunk [d][s], pad 40
  u16* pb = PBall + W * 640;           // this wave's P tile [16][40]

  // Q fragments (A-operand: m=lane&15, k=quad*8+j), 4 k-chunks of 32
  bf16x8 aq[4];
  {
    const u16* qp = qn + ((size_t)(b * L_ + q0 + mq)) * 4096 + h * 128 + qd * 8;
#pragma unroll
    for (int kc = 0; kc < 4; kc++) aq[kc] = ld8(qp + kc * 32);
  }

  f32x4 oacc[8] = {};
  float mi[4], li[4];
#pragma unroll
  for (int r = 0; r < 4; r++){ mi[r] = -1e30f; li[r] = 0.f; }

  const int nchunks = (WINS_ + qt * 64 + 63) / 32 + 1;   // block-uniform
  const int cpb = (nchunks + SPLIT_ - 1) / SPLIT_;       // block-uniform
  const int sc_beg = sp * cpb;
  const int sc_end = (sc_beg + cpb < nchunks) ? (sc_beg + cpb) : nchunks;
  const float scale = 0.08838834764831845f;
  const float L2E = 1.4426950408889634f;

  const int dd = lt & 127, sg = lt >> 7;   // V-load thread mapping (per group)
  u16 vv[16];                              // V prefetch (16 s for column dd)
  bf16x8 kf[2][4];                         // K fragment prefetch (32 VGPRs)

  auto loadV = [&](int sc){
    const int s0c = sc * 32;
#pragma unroll
    for (int j = 0; j < 16; j++){
      const int s = s0c + sg * 16 + j;
      if (s >= WINS_){
        vv[j] = vnew[((size_t)(b * L_ + (s - WINS_)) << 12) + h * 128 + dd];
      } else {
        const int scc = (s < SINK_) ? s : (s + L_);
        const size_t off = ((((size_t)b * S_ + scc) * H_ + h) << 7) + dd;
        vv[j] = mode ? f2bf(((const float*)cv)[off]) : ((const u16*)cv)[off];
      }
    }
  };

  auto loadK = [&](int sc){
    const int s0c = sc * 32;
#pragma unroll
    for (int st = 0; st < 2; st++){
      const int stile = s0c + st * 16;
      const int s = stile + mq;
      if (stile >= WINS_){
        const u16* kp = kn + ((size_t)(b * L_ + (s - WINS_)) << 12) + h * 128;
#pragma unroll
        for (int kc = 0; kc < 4; kc++) kf[st][kc] = ld8(kp + kc * 32 + qd * 8);
      } else if (mode){
        const int scc = (s < SINK_) ? s : (s + L_);
        const float* kp = (const float*)ck + ((((size_t)b * S_ + scc) * H_ + h) << 7);
#pragma unroll
        for (int kc = 0; kc < 4; kc++) kf[st][kc] = ld8f(kp + kc * 32 + qd * 8);
      } else {
        const int scc = (s < SINK_) ? s : (s + L_);
        const u16* kp = (const u16*)ck + ((((size_t)b * S_ + scc) * H_ + h) << 7);
#pragma unroll
        for (int kc = 0; kc < 4; kc++) kf[st][kc] = ld8(kp + kc * 32 + qd * 8);
      }
    }
  };

  if (sc_beg < sc_end){ loadV(sc_beg); loadK(sc_beg); }

  for (int scr = 0; scr < cpb; scr++){     // uniform trip count for barriers
    const int sc = sc_beg + scr;
    const int act = (sc < sc_end);
    const int s0 = sc * 32;

    __syncthreads();   // previous iteration's VT reads complete (all groups)
    if (act){
#pragma unroll
      for (int hv = 0; hv < 2; hv++){
        u16x8 pk;
#pragma unroll
        for (int j = 0; j < 8; j++) pk[j] = vv[hv * 8 + j];
        *(u16x8*)&VT[dd * 40 + sg * 16 + hv * 8] = pk;
      }
    }
    __syncthreads();   // VT staged (all groups)
    if (sc + 1 < sc_end) loadV(sc + 1);    // prefetch next V (vv regs free)

    if (act){
      // ---- QK^T from prefetched kf: logits[q][s], 2 s-tiles of 16 ----
      float lg[2][4];
#pragma unroll
      for (int st = 0; st < 2; st++){
        f32x4 a = {};
#pragma unroll
        for (int kc = 0; kc < 4; kc++)
          a = __builtin_amdgcn_mfma_f32_16x16x32_bf16(aq[kc], kf[st][kc], a, 0, 0, 0);
#pragma unroll
        for (int r = 0; r < 4; r++) lg[st][r] = a[r] * scale;
      }
      // kf consumed -> issue next chunk's K loads; latency hides under
      // softmax + PV + next barrier + VT stage.
      if (sc + 1 < sc_end) loadK(sc + 1);

      // ---- causal mask (only near/past the frontier) ----
      if (s0 + 31 > WINS_ + q0){
#pragma unroll
        for (int st = 0; st < 2; st++){
          const int s = s0 + st * 16 + mq;
#pragma unroll
          for (int r = 0; r < 4; r++)
            if (s > WINS_ + (q0 + qd * 4 + r)) lg[st][r] = -1e30f;
        }
      }
      // ---- online softmax (row r spread over 16 mq lanes within quad) ----
      float p[2][4];
#pragma unroll
      for (int r = 0; r < 4; r++){
        float mx = fmaxf(lg[0][r], lg[1][r]);
#pragma unroll
        for (int m = 1; m < 16; m <<= 1) mx = fmaxf(mx, __shfl_xor(mx, m, 64));
        const float mnew = fmaxf(mi[r], mx);
        const float alpha = exp2f((mi[r] - mnew) * L2E);
        mi[r] = mnew;
        float s_ = 0.f;
#pragma unroll
        for (int st = 0; st < 2; st++){
          p[st][r] = exp2f((lg[st][r] - mnew) * L2E);
          s_ += p[st][r];
        }
#pragma unroll
        for (int m = 1; m < 16; m <<= 1) s_ += __shfl_xor(s_, m, 64);
        li[r] = li[r] * alpha + s_;
#pragma unroll
        for (int nt = 0; nt < 8; nt++) oacc[nt][r] *= alpha;
      }
      // ---- P: C-layout -> A-layout via wave-private LDS ----
#pragma unroll
      for (int st = 0; st < 2; st++)
#pragma unroll
        for (int r = 0; r < 4; r++)
          pb[(qd * 4 + r) * 40 + st * 16 + mq] = f2bf(p[st][r]);
      asm volatile("" ::: "memory");
      u16x8 pr;
#pragma unroll
      for (int j = 0; j < 8; j++) pr[j] = pb[mq * 40 + qd * 8 + j];
      bf16x8 ap = __builtin_bit_cast(bf16x8, pr);
      // ---- PV: O[q][d] += P * V ----
#pragma unroll
      for (int nt = 0; nt < 8; nt++){
        bf16x8 bv = ld8(&VT[(nt * 16 + mq) * 40 + qd * 8]);
        oacc[nt] = __builtin_amdgcn_mfma_f32_16x16x32_bf16(ap, bv, oacc[nt], 0, 0, 0);
      }
    }
  }

  // ---- intra-block merge of the 4 S-split partials ----
  __syncthreads();                       // (A) main phase done, VT/PB free
  if (mq == 0){
#pragma unroll
    for (int r = 0; r < 4; r++){
      const int lr = w * 16 + qd * 4 + r;     // local row 0..63
      ML[(sp * 64 + lr) * 2 + 0] = mi[r];
      ML[(sp * 64 + lr) * 2 + 1] = li[r];
    }
  }
  __syncthreads();                       // (B) ML visible

  float gl[4], wgt[4];
#pragma unroll
  for (int r = 0; r < 4; r++){
    const int lr = w * 16 + qd * 4 + r;
    float m_ = -1e30f;
#pragma unroll
    for (int p = 0; p < SPLIT_; p++) m_ = fmaxf(m_, ML[(p * 64 + lr) * 2 + 0]);
    float l_ = 0.f;
#pragma unroll
    for (int p = 0; p < SPLIT_; p++)
      l_ += exp2f((ML[(p * 64 + lr) * 2 + 0] - m_) * L2E) * ML[(p * 64 + lr) * 2 + 1];
    gl[r] = l_;
    wgt[r] = exp2f((mi[r] - m_) * L2E);
  }

  // accumulation rounds: single-owner RMW per element, barrier-separated
#pragma unroll
  for (int p = 0; p < SPLIT_; p++){
    if (sp == p){
#pragma unroll
      for (int nt = 0; nt < 8; nt++)
#pragma unroll
        for (int r = 0; r < 4; r++){
          const int off = (w * 16 + qd * 4 + r) * 128 + nt * 16 + mq;
          const float v = wgt[r] * oacc[nt][r];
          if (p == 0) OB[off] = v;
          else        OB[off] += v;
        }
    }
    __syncthreads();
  }

  // final write by group 0
  if (sp == 0){
#pragma unroll
    for (int nt = 0; nt < 8; nt++)
#pragma unroll
      for (int r = 0; r < 4; r++){
        const int lr = w * 16 + qd * 4 + r;
        const int qrow = qt * 64 + lr;
        const float v = OB[lr * 128 + nt * 16 + mq] / gl[r];
        ao[((size_t)(b * L_ + qrow) << 12) + h * 128 + nt * 16 + mq] = f2bf(v);
      }
  }
}

// ---------------------------------------------------------------------------
extern "C" void kernel_launch(void* const* d_in, const int* in_sizes, int n_in,
                              void* d_out, int out_size, void* d_ws, size_t ws_size,
                              hipStream_t stream){
  (void)in_sizes; (void)n_in; (void)out_size;
  const void* x  = d_in[0];
  const void* ck = d_in[1];
  const void* cv = d_in[2];
  const void* Wq = d_in[3];
  const void* Wk = d_in[4];
  const void* Wv = d_in[5];
  const void* Wo = d_in[6];
  const void* qw = d_in[7];
  const void* kw = d_in[8];

  const size_t WT_E = 4096ull * 4096;    // one transposed weight (bf16 elems)
  const size_t BUF  = (size_t)M_ * 4096; // 2.10M elems

  uint32_t* flag = (uint32_t*)d_ws;
  u16* ws0 = (u16*)d_ws + 64;            // skip 128B for flag

  detect_k<<<1, 64, 0, stream>>>((const u16*)x, flag);

  // Fused path needs 3 transposed weights resident: 128 + (3*WT_E + 6*BUF)*2 B
  const size_t need_fused = 128 + (3 * WT_E + 6 * BUF) * 2;
  if (ws_size >= need_fused){
    u16* WT3 = ws0;                      // 3 x WT_E (Wq^T, Wk^T, Wv^T; Wo^T reuses)
    u16* qkv = WT3 + 3 * WT_E;           // 3 x BUF (q_raw, k_raw, v)
    u16* qn  = qkv + 3 * BUF;            // 2 x BUF (qn, kn)
    u16* ao  = qn + 2 * BUF;             // 1 x BUF

    transpose_k<<<dim3(64, 64), 256, 0, stream>>>(Wq, WT3, flag);
    transpose_k<<<dim3(64, 64), 256, 0, stream>>>(Wk, WT3 + WT_E, flag);
    transpose_k<<<dim3(64, 64), 256, 0, stream>>>(Wv, WT3 + 2 * WT_E, flag);
    gemm64_k<<<dim3(192, 8), 256, 0, stream>>>(x, WT3, qkv, flag, 1, 0);

    rmsnorm_k<<<dim3(4096, 2), 256, 0, stream>>>(qkv, qn, qw, kw, flag);

    attn_k<<<dim3(256), 1024, 0, stream>>>(qn, qn + BUF, qkv + 2 * BUF,
                                           ck, cv, ao, flag);

    transpose_k<<<dim3(64, 64), 256, 0, stream>>>(Wo, WT3, flag);
    gemm64_k<<<dim3(64, 8), 256, 0, stream>>>(ao, WT3, d_out, flag, 0, 1);
  } else {
    // Fallback: sequential per-weight path
    u16* WT  = ws0;                      // WT_E elems (reused per weight)
    u16* qkv = WT + WT_E;                // 3 x BUF
    u16* qn  = qkv + 3 * BUF;            // 2 x BUF
    u16* ao  = qn + 2 * BUF;             // 1 x BUF

    transpose_k<<<dim3(64, 64), 256, 0, stream>>>(Wq, WT, flag);
    gemm64_k<<<dim3(64, 8), 256, 0, stream>>>(x, WT, qkv, flag, 1, 0);
    transpose_k<<<dim3(64, 64), 256, 0, stream>>>(Wk, WT, flag);
    gemm64_k<<<dim3(64, 8), 256, 0, stream>>>(x, WT, qkv + BUF, flag, 1, 0);
    transpose_k<<<dim3(64, 64), 256, 0, stream>>>(Wv, WT, flag);
    gemm64_k<<<dim3(64, 8), 256, 0, stream>>>(x, WT, qkv + 2 * BUF, flag, 1, 0);

    rmsnorm_k<<<dim3(4096, 2), 256, 0, stream>>>(qkv, qn, qw, kw, flag);

    attn_k<<<dim3(256), 1024, 0, stream>>>(qn, qn + BUF, qkv + 2 * BUF,
                                           ck, cv, ao, flag);

    transpose_k<<<dim3(64, 64), 256, 0, stream>>>(Wo, WT, flag);
    gemm64_k<<<dim3(64, 8), 256, 0, stream>>>(ao, WT, d_out, flag, 0, 1);
  }
}